// Round 4
// baseline (158.885 us; speedup 1.0000x reference)
//
#include <hip/hip_runtime.h>

typedef unsigned int uintx4 __attribute__((ext_vector_type(4)));

// Bit-exact replica of XLA:CPU's vectorized f32 exp AS COMPILED with
// fast-math contraction (== Eigen classic pexp_float with pmadd=FMA on AVX2).
// Non-FMA ops must stay un-contracted -> pragma contract(off) + explicit fmaf.
__device__ __forceinline__ float xla_expf(float xin) {
#pragma clang fp contract(off)
  float xc = fminf(xin, 88.3762626647950f);
  xc = fmaxf(xc, -88.3762626647949f);
  float m = floorf(fmaf(xc, 1.44269504088896341f, 0.5f));
  float r = fmaf(m, -0.693359375f, xc);
  r = fmaf(m, 2.12194440e-4f, r);
  float r2 = r * r;
  float y = 1.9875691500E-4f;            // p0
  y = fmaf(y, r, 1.3981999507E-3f);      // p1
  y = fmaf(y, r, 8.3334519073E-3f);      // p2
  y = fmaf(y, r, 4.1665795894E-2f);      // p3
  y = fmaf(y, r, 1.6666665459E-1f);      // p4
  y = fmaf(y, r, 5.0000001201E-1f);      // p5
  y = fmaf(y, r2, r);
  y = y + 1.0f;
  int n = (int)m;
  float twon = __int_as_float((n + 127) << 23);
  float res = y * twon;
  return fmaxf(res, xin);                // final pmax vs UNCLAMPED input
}

__device__ __forceinline__ float xla_sigmoid(float f) {
#pragma clang fp contract(off)
  float e = xla_expf(-f);
  float denom = 1.0f + e;
  return 1.0f / denom;
}

// Each lane owns HALF a value: 16 consecutive bit-floats = 4x uintx4 = 64B.
// quad index q: floats [16q, 16q+16). value v = q>>1, half h = q&1
// (h=0 -> bits 31..16, h=1 -> bits 15..0, MSB first).
// Lane pair (2j, 2j+1) holds the two halves of one value; one shfl_xor(,1)
// OR-merges them. Pulse decode: 1.0f = 0x3F800000 -> bit = (u>>23)&1.
__global__ void __launch_bounds__(256) spike_sigmoid_kernel(
    const uintx4* __restrict__ in, uintx4* __restrict__ out, int nq) {
  int q = blockIdx.x * 256 + threadIdx.x;
  if (q >= nq) return;                   // grid is exact; guard is free
  const uintx4* p = in + (size_t)q * 4;
  uintx4 a = p[0], b = p[1], c = p[2], d = p[3];

  // Horner MSB-first: after 16 steps, float j sits at bit 15-j.
  unsigned w = 0;
  w = (w << 1) | ((a.x >> 23) & 1u);
  w = (w << 1) | ((a.y >> 23) & 1u);
  w = (w << 1) | ((a.z >> 23) & 1u);
  w = (w << 1) | ((a.w >> 23) & 1u);
  w = (w << 1) | ((b.x >> 23) & 1u);
  w = (w << 1) | ((b.y >> 23) & 1u);
  w = (w << 1) | ((b.z >> 23) & 1u);
  w = (w << 1) | ((b.w >> 23) & 1u);
  w = (w << 1) | ((c.x >> 23) & 1u);
  w = (w << 1) | ((c.y >> 23) & 1u);
  w = (w << 1) | ((c.z >> 23) & 1u);
  w = (w << 1) | ((c.w >> 23) & 1u);
  w = (w << 1) | ((d.x >> 23) & 1u);
  w = (w << 1) | ((d.y >> 23) & 1u);
  w = (w << 1) | ((d.z >> 23) & 1u);
  w = (w << 1) | ((d.w >> 23) & 1u);

  int h = q & 1;
  unsigned u = h ? w : (w << 16);
  u |= __shfl_xor(u, 1);                 // merge the two halves

  float s = xla_sigmoid(__uint_as_float(u));
  unsigned sb = __float_as_uint(s);
  unsigned t = h ? (sb & 0xFFFFu) : (sb >> 16);  // my half's 16 bits, MSB first

  // bit j (j=0..15) -> float 1.0f/0.0f via (0-bit)&0x3F800000
  uintx4 o0, o1, o2, o3;
  o0.x = (0u - ((t >> 15) & 1u)) & 0x3F800000u;
  o0.y = (0u - ((t >> 14) & 1u)) & 0x3F800000u;
  o0.z = (0u - ((t >> 13) & 1u)) & 0x3F800000u;
  o0.w = (0u - ((t >> 12) & 1u)) & 0x3F800000u;
  o1.x = (0u - ((t >> 11) & 1u)) & 0x3F800000u;
  o1.y = (0u - ((t >> 10) & 1u)) & 0x3F800000u;
  o1.z = (0u - ((t >>  9) & 1u)) & 0x3F800000u;
  o1.w = (0u - ((t >>  8) & 1u)) & 0x3F800000u;
  o2.x = (0u - ((t >>  7) & 1u)) & 0x3F800000u;
  o2.y = (0u - ((t >>  6) & 1u)) & 0x3F800000u;
  o2.z = (0u - ((t >>  5) & 1u)) & 0x3F800000u;
  o2.w = (0u - ((t >>  4) & 1u)) & 0x3F800000u;
  o3.x = (0u - ((t >>  3) & 1u)) & 0x3F800000u;
  o3.y = (0u - ((t >>  2) & 1u)) & 0x3F800000u;
  o3.z = (0u - ((t >>  1) & 1u)) & 0x3F800000u;
  o3.w = (0u - ((t      ) & 1u)) & 0x3F800000u;

  uintx4* po = out + (size_t)q * 4;
  __builtin_nontemporal_store(o0, po + 0);
  __builtin_nontemporal_store(o1, po + 1);
  __builtin_nontemporal_store(o2, po + 2);
  __builtin_nontemporal_store(o3, po + 3);
}

extern "C" void kernel_launch(void* const* d_in, const int* in_sizes, int n_in,
                              void* d_out, int out_size, void* d_ws, size_t ws_size,
                              hipStream_t stream) {
  const uintx4* in = (const uintx4*)d_in[0];
  uintx4* out = (uintx4*)d_out;
  int nq = in_sizes[0] / 16;             // 4,000,000 quad-groups (16 floats each)
  dim3 block(256);
  dim3 grid((nq + 255) / 256);           // 15625 blocks, exact
  spike_sigmoid_kernel<<<grid, block, 0, stream>>>(in, out, nq);
}

// Round 5
// 75.602 us; speedup vs baseline: 2.1016x; 2.1016x over previous
//
#include <hip/hip_runtime.h>

// Bit-exact replica of XLA:CPU's vectorized f32 exp AS COMPILED with
// fast-math contraction (== Eigen classic pexp_float with pmadd=FMA on AVX2).
// Non-FMA ops must stay un-contracted -> pragma contract(off) + explicit fmaf.
__device__ __forceinline__ float xla_expf(float xin) {
#pragma clang fp contract(off)
  float xc = fminf(xin, 88.3762626647950f);
  xc = fmaxf(xc, -88.3762626647949f);
  float m = floorf(fmaf(xc, 1.44269504088896341f, 0.5f));
  float r = fmaf(m, -0.693359375f, xc);
  r = fmaf(m, 2.12194440e-4f, r);
  float r2 = r * r;
  float y = 1.9875691500E-4f;            // p0
  y = fmaf(y, r, 1.3981999507E-3f);      // p1
  y = fmaf(y, r, 8.3334519073E-3f);      // p2
  y = fmaf(y, r, 4.1665795894E-2f);      // p3
  y = fmaf(y, r, 1.6666665459E-1f);      // p4
  y = fmaf(y, r, 5.0000001201E-1f);      // p5
  y = fmaf(y, r2, r);
  y = y + 1.0f;
  int n = (int)m;
  float twon = __int_as_float((n + 127) << 23);
  float res = y * twon;
  return fmaxf(res, xin);                // final pmax vs UNCLAMPED input
}

__device__ __forceinline__ float xla_sigmoid(float f) {
#pragma clang fp contract(off)
  float e = xla_expf(-f);
  float denom = 1.0f + e;
  return 1.0f / denom;
}

// Segment = 64 consecutive bit-floats = 2 values. Lane j reads float j
// (fully coalesced 4B). ballot(pulse>0.5): bit j = value_{j>>5} bit (31-(j&31))
// => lo32/hi32 bit-reversed are the two value u32s. No DS/shuffle ops at all.
// Each lane sigmoids its half-wave's value (32x redundant, VALU has headroom),
// extracts bit (31-(lane&31)), stores float j back. NT stores, full lines.
#define KSEG 8

__global__ void __launch_bounds__(256) spike_sigmoid_kernel(
    const float* __restrict__ in, float* __restrict__ out, int nseg) {
  int W = (blockIdx.x * 256 + threadIdx.x) >> 6;  // global wave id
  int lane = threadIdx.x & 63;
  int seg0 = W * KSEG;
  if (seg0 >= nseg) return;
  size_t base = (size_t)seg0 * 64 + lane;
  int sel = lane >> 5;
  int bitpos = 31 - (lane & 31);

  if (seg0 + KSEG <= nseg) {
    float f[KSEG];
#pragma unroll
    for (int k = 0; k < KSEG; ++k) f[k] = in[base + (size_t)k * 64];
#pragma unroll
    for (int k = 0; k < KSEG; ++k) {
      unsigned long long b = __ballot(f[k] > 0.5f);
      unsigned u0 = __brev((unsigned)b);
      unsigned u1 = __brev((unsigned)(b >> 32));
      unsigned u = sel ? u1 : u0;
      float s = xla_sigmoid(__uint_as_float(u));
      unsigned sb = __float_as_uint(s);
      float o = (float)((sb >> bitpos) & 1u);
      __builtin_nontemporal_store(o, &out[base + (size_t)k * 64]);
    }
  } else {
    for (int k = 0; k < KSEG && seg0 + k < nseg; ++k) {
      float fk = in[base + (size_t)k * 64];
      unsigned long long b = __ballot(fk > 0.5f);
      unsigned u0 = __brev((unsigned)b);
      unsigned u1 = __brev((unsigned)(b >> 32));
      unsigned u = sel ? u1 : u0;
      float s = xla_sigmoid(__uint_as_float(u));
      unsigned sb = __float_as_uint(s);
      float o = (float)((sb >> bitpos) & 1u);
      __builtin_nontemporal_store(o, &out[base + (size_t)k * 64]);
    }
  }
}

extern "C" void kernel_launch(void* const* d_in, const int* in_sizes, int n_in,
                              void* d_out, int out_size, void* d_ws, size_t ws_size,
                              hipStream_t stream) {
  const float* in = (const float*)d_in[0];
  float* out = (float*)d_out;
  int nseg = in_sizes[0] / 64;                    // 1,000,000 segments (2 values each)
  int waves = (nseg + KSEG - 1) / KSEG;           // 125,000
  int threads = waves * 64;                       // 8,000,000
  dim3 block(256);
  dim3 grid((threads + 255) / 256);               // 31,250 blocks
  spike_sigmoid_kernel<<<grid, block, 0, stream>>>(in, out, nseg);
}

// Round 6
// 75.092 us; speedup vs baseline: 2.1159x; 1.0068x over previous
//
#include <hip/hip_runtime.h>

// Bit-exact replica of XLA:CPU's vectorized f32 exp AS COMPILED with
// fast-math contraction (== Eigen classic pexp_float with pmadd=FMA on AVX2).
// Non-FMA ops must stay un-contracted -> pragma contract(off) + explicit fmaf.
__device__ __forceinline__ float xla_expf(float xin) {
#pragma clang fp contract(off)
  float xc = fminf(xin, 88.3762626647950f);
  xc = fmaxf(xc, -88.3762626647949f);
  float m = floorf(fmaf(xc, 1.44269504088896341f, 0.5f));
  float r = fmaf(m, -0.693359375f, xc);
  r = fmaf(m, 2.12194440e-4f, r);
  float r2 = r * r;
  float y = 1.9875691500E-4f;            // p0
  y = fmaf(y, r, 1.3981999507E-3f);      // p1
  y = fmaf(y, r, 8.3334519073E-3f);      // p2
  y = fmaf(y, r, 4.1665795894E-2f);      // p3
  y = fmaf(y, r, 1.6666665459E-1f);      // p4
  y = fmaf(y, r, 5.0000001201E-1f);      // p5
  y = fmaf(y, r2, r);
  y = y + 1.0f;
  int n = (int)m;
  float twon = __int_as_float((n + 127) << 23);
  float res = y * twon;
  return fmaxf(res, xin);                // final pmax vs UNCLAMPED input
}

__device__ __forceinline__ float xla_sigmoid(float f) {
#pragma clang fp contract(off)
  float e = xla_expf(-f);
  float denom = 1.0f + e;
  return 1.0f / denom;
}

// Segment = 64 consecutive bit-floats = 2 values. Lane j reads float j of the
// segment (coalesced 4B). ballot(pulse>0.5) -> lo32/hi32 bit-reversed are the
// two value words (wave-uniform). Per 8-segment iteration: 16 uniform values;
// lane L selects value L>>2 via a 15-cndmask static tree and computes ONE
// sigmoid (4x redundancy, was 32x). Redistribute: lane j / segment k needs
// value 2k+(j>>5), held by lanes 4w..4w+3 -> shfl from lane 8k+4*(j>>5).
#define KSEG 8

__global__ void __launch_bounds__(256) spike_sigmoid_kernel(
    const float* __restrict__ in, float* __restrict__ out, int nseg) {
  int W = (blockIdx.x * 256 + threadIdx.x) >> 6;  // global wave id
  int lane = threadIdx.x & 63;
  int seg0 = W * KSEG;
  if (seg0 >= nseg) return;
  size_t base = (size_t)seg0 * 64 + lane;
  int sel = lane >> 5;
  int bitpos = 31 - (lane & 31);
  int srcbase = sel * 4;

  if (seg0 + KSEG <= nseg) {
    float f[KSEG];
#pragma unroll
    for (int k = 0; k < KSEG; ++k) f[k] = in[base + (size_t)k * 64];

    unsigned u[16];
#pragma unroll
    for (int k = 0; k < KSEG; ++k) {
      unsigned long long b = __ballot(f[k] > 0.5f);
      u[2 * k]     = __brev((unsigned)b);
      u[2 * k + 1] = __brev((unsigned)(b >> 32));
    }

    // Static select tree: lane L takes value V = L>>2.
    // V bit0=L bit2, bit1=L bit3, bit2=L bit4, bit3=L bit5.
    bool p2 = (lane >> 2) & 1, p3 = (lane >> 3) & 1;
    bool p4 = (lane >> 4) & 1, p5 = (lane >> 5) & 1;
    unsigned a0 = p2 ? u[1]  : u[0],  a1 = p2 ? u[3]  : u[2];
    unsigned a2 = p2 ? u[5]  : u[4],  a3 = p2 ? u[7]  : u[6];
    unsigned a4 = p2 ? u[9]  : u[8],  a5 = p2 ? u[11] : u[10];
    unsigned a6 = p2 ? u[13] : u[12], a7 = p2 ? u[15] : u[14];
    unsigned b0 = p3 ? a1 : a0, b1 = p3 ? a3 : a2;
    unsigned b2 = p3 ? a5 : a4, b3 = p3 ? a7 : a6;
    unsigned c0 = p4 ? b1 : b0, c1 = p4 ? b3 : b2;
    unsigned v  = p5 ? c1 : c0;

    float s = xla_sigmoid(__uint_as_float(v));
    unsigned sb = __float_as_uint(s);

#pragma unroll
    for (int k = 0; k < KSEG; ++k) {
      unsigned x = (unsigned)__shfl((int)sb, 8 * k + srcbase);
      float o = (float)((x >> bitpos) & 1u);
      __builtin_nontemporal_store(o, &out[base + (size_t)k * 64]);
    }
  } else {
    // Tail (not taken for nseg=1e6, kept for generality). Wave-uniform trip.
    for (int k = 0; k < KSEG && seg0 + k < nseg; ++k) {
      float fk = in[base + (size_t)k * 64];
      unsigned long long b = __ballot(fk > 0.5f);
      unsigned u0 = __brev((unsigned)b);
      unsigned u1 = __brev((unsigned)(b >> 32));
      unsigned uu = sel ? u1 : u0;
      float s = xla_sigmoid(__uint_as_float(uu));
      unsigned sb = __float_as_uint(s);
      float o = (float)((sb >> bitpos) & 1u);
      __builtin_nontemporal_store(o, &out[base + (size_t)k * 64]);
    }
  }
}

extern "C" void kernel_launch(void* const* d_in, const int* in_sizes, int n_in,
                              void* d_out, int out_size, void* d_ws, size_t ws_size,
                              hipStream_t stream) {
  const float* in = (const float*)d_in[0];
  float* out = (float*)d_out;
  int nseg = in_sizes[0] / 64;                    // 1,000,000 segments (2 values each)
  int waves = (nseg + KSEG - 1) / KSEG;           // 125,000
  long long threads = (long long)waves * 64;      // 8,000,000
  dim3 block(256);
  dim3 grid((unsigned)((threads + 255) / 256));   // 31,250 blocks
  spike_sigmoid_kernel<<<grid, block, 0, stream>>>(in, out, nseg);
}